// Round 4
// baseline (429.650 us; speedup 1.0000x reference)
//
#include <hip/hip_runtime.h>
#include <hip/hip_bf16.h>

// ScalarQLinear via int8 MFMA, round 9:
//   R8 probe: quantize is NOT the residual (grid-stride change = noise);
//   gemm at 127us vs 70us i8 floor is the only lever. Pipe arithmetic for
//   R5 per CU: MFMA 167k cy vs LDS 192k cy (12288 ds_read_b128 x 12cy +
//   staging writes) -> LDS pipe binds, every byte read 2x.
//   R9: remove A from LDS entirely (keep R5's B path/barriers/epilogue
//   byte-exact). A-fragments load straight global->VGPR per wave with a
//   rolling 4-frag prefetch: h1 frags load under h0's 32 MFMAs (~1300 cy
//   cover >> L2 latency), next-step h0 under h1+barrier. A panel (512KB/
//   m-block) stays L2-resident across the 16 n-blocks sharing it.
//   LDS read instrs -33%, LDS 48->32KB, acc 128 AGPR + ~110 VGPR keeps
//   2 blocks/CU. Quantize reverted to original R5 version.

typedef int int32x4 __attribute__((ext_vector_type(4)));

#define MDIM 8192
#define NDIM 4096
#define KDIM 4096

__device__ __forceinline__ void async_copy16(const void* g, void* l) {
  __builtin_amdgcn_global_load_lds(
      (const __attribute__((address_space(1))) void*)g,
      (__attribute__((address_space(3))) void*)l, 16, 0, 0);
}

__device__ __forceinline__ unsigned pack4(float a, float b, float c, float d) {
  return ((unsigned)((int)a & 0xff)) | ((unsigned)((int)b & 0xff) << 8) |
         ((unsigned)((int)c & 0xff) << 16) | ((unsigned)((int)d & 0xff) << 24);
}

// --- K1: fused quantizers. Blocks [0,4096): w rows; [4096,12288): x rows. ---
__global__ __launch_bounds__(256) void quantize_all(
    const float* __restrict__ w, const float* __restrict__ x,
    unsigned* __restrict__ qw, unsigned* __restrict__ qx,
    float* __restrict__ scale, float* __restrict__ sx) {
  const int t = threadIdx.x;
  __shared__ float wred[4];
  if (blockIdx.x < NDIM) {
    const int row = blockIdx.x;
    const float4* wr = (const float4*)(w + (size_t)row * KDIM);
    float4 v[4];
    float ss = 0.f;
#pragma unroll
    for (int i = 0; i < 4; ++i) {
      v[i] = wr[t + 256 * i];
      ss += v[i].x * v[i].x + v[i].y * v[i].y + v[i].z * v[i].z + v[i].w * v[i].w;
    }
#pragma unroll
    for (int m = 32; m >= 1; m >>= 1) ss += __shfl_xor(ss, m, 64);
    if ((t & 63) == 0) wred[t >> 6] = ss;
    __syncthreads();
    const float safe = fmaxf(sqrtf(wred[0] + wred[1] + wred[2] + wred[3]), 1e-8f);
    unsigned* qr = qw + (size_t)row * (KDIM / 4);
#pragma unroll
    for (int i = 0; i < 4; ++i) {
      float q0 = fminf(fmaxf(rintf(v[i].x / safe * 60.0f), -8.f), 7.f);
      float q1 = fminf(fmaxf(rintf(v[i].y / safe * 60.0f), -8.f), 7.f);
      float q2 = fminf(fmaxf(rintf(v[i].z / safe * 60.0f), -8.f), 7.f);
      float q3 = fminf(fmaxf(rintf(v[i].w / safe * 60.0f), -8.f), 7.f);
      qr[t + 256 * i] = pack4(q0, q1, q2, q3);
    }
    if (t == 0) scale[row] = safe / 60.0f;
  } else {
    const int row = blockIdx.x - NDIM;
    const float4* xr = (const float4*)(x + (size_t)row * KDIM);
    float4 v[4];
    float am = 0.f;
#pragma unroll
    for (int i = 0; i < 4; ++i) {
      v[i] = xr[t + 256 * i];
      am = fmaxf(am, fmaxf(fmaxf(fabsf(v[i].x), fabsf(v[i].y)),
                           fmaxf(fabsf(v[i].z), fabsf(v[i].w))));
    }
#pragma unroll
    for (int m = 32; m >= 1; m >>= 1) am = fmaxf(am, __shfl_xor(am, m, 64));
    if ((t & 63) == 0) wred[t >> 6] = am;
    __syncthreads();
    const float amax =
        fmaxf(fmaxf(fmaxf(wred[0], wred[1]), fmaxf(wred[2], wred[3])), 1e-20f);
    const float r = 127.0f / amax;
    unsigned* qr = qx + (size_t)row * (KDIM / 4);
#pragma unroll
    for (int i = 0; i < 4; ++i) {
      float q0 = fminf(fmaxf(rintf(v[i].x * r), -127.f), 127.f);
      float q1 = fminf(fmaxf(rintf(v[i].y * r), -127.f), 127.f);
      float q2 = fminf(fmaxf(rintf(v[i].z * r), -127.f), 127.f);
      float q3 = fminf(fmaxf(rintf(v[i].w * r), -127.f), 127.f);
      qr[t + 256 * i] = pack4(q0, q1, q2, q3);
    }
    if (t == 0) sx[row] = amax / 127.0f;
  }
}

// --- K2: C[m,n] = sx[m]*scale[n]*dot_i8(A[m,:],B[n,:]) + bias[n] ---
// Block tile 128(M) x 256(N), BK=128; 4 waves each 64x128 (acc 4x8).
// B staged in LDS (R5 path, swizzled, 0 conflicts); A direct global->VGPR.
__global__ __launch_bounds__(256, 2) void gemm_i8(const char* __restrict__ A,
                                                  const char* __restrict__ B,
                                                  const float* __restrict__ sx,
                                                  const float* __restrict__ scale,
                                                  const float* __restrict__ bias,
                                                  float* __restrict__ C) {
  __shared__ __align__(16) char sB[256 * 128];  // 32 KB (w tile only)
  const int tid = threadIdx.x;
  const int m0 = blockIdx.y * 128;
  const int n0 = blockIdx.x * 256;

  // B staging: lane tid -> LDS slot (row = issue*32 + tid>>3, chunk = tid&7);
  // phys_chunk = logical_chunk ^ (row&7) applied at the SOURCE.
  const int r0 = tid >> 3;                              // 0..31
  const int c16 = ((tid & 7) ^ ((tid >> 3) & 7)) * 16;  // swizzled source col
  const char* gB = B + (size_t)(n0 + r0) * KDIM + c16;
  char* lB = sB + tid * 16;

  const int lane = tid & 63;
  const int wid = tid >> 6;
  const int wm = (wid & 1) * 64;    // wave M offset: 0 / 64
  const int wn = (wid >> 1) * 128;  // wave N offset: 0 / 128
  const int fr = lane & 15;  // A: m, B: n
  const int q = lane >> 4;   // k-quad
  const int sw = fr & 7;
  const int ph0 = ((q) ^ sw) * 16;      // B phys chunk offset, k-half 0
  const int ph1 = ((4 + q) ^ sw) * 16;  // B phys chunk offset, k-half 1

  // A direct: lane holds A[m0+wm+i*16+fr][kt*128 + h*64 + q*16 .. +16]
  const char* gA = A + (size_t)(m0 + wm + fr) * KDIM + q * 16;

  int32x4 acc[4][8] = {};
  int32x4 af[4], an[4], bg[8];

  // preload step-0 h0 fragments
#pragma unroll
  for (int i = 0; i < 4; ++i)
    af[i] = *(const int32x4*)(gA + (size_t)i * (16 * KDIM));

  for (int kt = 0; kt < KDIM / 128; ++kt) {  // 32 iterations
    __syncthreads();  // prior-iter LDS reads done before overwrite
#pragma unroll
    for (int i = 0; i < 8; ++i)
      async_copy16(gB + (size_t)(32 * i) * KDIM, lB + i * 4096);
    __syncthreads();  // vmcnt(0) drain + barrier
    gB += 128;

    // ---- k-half 0: prefetch h1 A-frags, B from LDS, 32 MFMA ----
#pragma unroll
    for (int i = 0; i < 4; ++i)
      an[i] = *(const int32x4*)(gA + (size_t)i * (16 * KDIM) + 64);
#pragma unroll
    for (int j = 0; j < 8; ++j)
      bg[j] = *(const int32x4*)&sB[(wn + j * 16 + fr) * 128 + ph0];
#pragma unroll
    for (int i = 0; i < 4; ++i)
#pragma unroll
      for (int j = 0; j < 8; ++j)
        acc[i][j] =
            __builtin_amdgcn_mfma_i32_16x16x64_i8(af[i], bg[j], acc[i][j], 0, 0, 0);

    // ---- k-half 1: prefetch next-step h0 A-frags, B from LDS, 32 MFMA ----
    // (last iter's +128 prefetch lands in qw region: allocated, unused)
#pragma unroll
    for (int i = 0; i < 4; ++i)
      af[i] = *(const int32x4*)(gA + (size_t)i * (16 * KDIM) + 128);
#pragma unroll
    for (int j = 0; j < 8; ++j)
      bg[j] = *(const int32x4*)&sB[(wn + j * 16 + fr) * 128 + ph1];
#pragma unroll
    for (int i = 0; i < 4; ++i)
#pragma unroll
      for (int j = 0; j < 8; ++j)
        acc[i][j] =
            __builtin_amdgcn_mfma_i32_16x16x64_i8(an[i], bg[j], acc[i][j], 0, 0, 0);

    gA += 128;
  }

  // epilogue: C/D layout col = lane&15, row = quad*4 + reg (shape-determined)
  float scl[8], bs[8];
#pragma unroll
  for (int j = 0; j < 8; ++j) {
    const int n = n0 + wn + j * 16 + fr;
    scl[j] = scale[n];
    bs[j] = bias[n];
  }
  const int mrow = q * 4;
#pragma unroll
  for (int i = 0; i < 4; ++i) {
#pragma unroll
    for (int r = 0; r < 4; ++r) {
      const size_t m = (size_t)(m0 + wm + i * 16 + mrow + r);
      const float sxm = sx[m];
      float* crow = C + m * NDIM + (n0 + wn + fr);
#pragma unroll
      for (int j = 0; j < 8; ++j)
        crow[j * 16] = (float)acc[i][j][r] * (sxm * scl[j]) + bs[j];
    }
  }
}

extern "C" void kernel_launch(void* const* d_in, const int* in_sizes, int n_in,
                              void* d_out, int out_size, void* d_ws, size_t ws_size,
                              hipStream_t stream) {
  (void)in_sizes; (void)n_in; (void)out_size; (void)ws_size;
  const float* x = (const float*)d_in[0];     // [8192, 4096] fp32
  const float* w = (const float*)d_in[1];     // [4096, 4096] fp32
  const float* bias = (const float*)d_in[2];  // [4096] fp32
  float* out = (float*)d_out;                 // [8192, 4096] fp32

  char* ws = (char*)d_ws;
  char* qx = ws;                                           // 32 MB int8
  char* qw = ws + (size_t)33554432;                        // 16 MB int8
  float* sx = (float*)(ws + (size_t)50331648);             // 32 KB
  float* scale = (float*)(ws + (size_t)50331648 + 65536);  // 16 KB

  quantize_all<<<NDIM + MDIM, 256, 0, stream>>>(w, x, (unsigned*)qw,
                                                (unsigned*)qx, scale, sx);
  dim3 grid(NDIM / 256, MDIM / 128);  // (16, 64)
  gemm_i8<<<grid, 256, 0, stream>>>(qx, qw, sx, scale, bias, out);
}

// Round 5
// 389.155 us; speedup vs baseline: 1.1041x; 1.1041x over previous
//
#include <hip/hip_runtime.h>
#include <hip/hip_bf16.h>

// ScalarQLinear via int8 MFMA, round 10:
//   R9 post-mortem: A-direct-from-global regressed (189us, MfmaUtil 30%) --
//   16-segment uncoalesced A loads + prefetch distance < L2 latency. Reverted.
//   R5 model refined: per-CU MFMA 167k cy + LDS 144k cy vs measured 305k cy
//   => pipes run SERIALIZED. Barriers phase-align waves within a block and
//   only 2 blocks/CU (224 regs/wave caps 8 wave-slots) => not enough phase
//   diversity to fill MFMA and LDS pipes concurrently.
//   R10: shrink the barrier domain, keep wave code byte-identical to R5:
//   - 128-thread blocks (2 waves), tile 128x128; wave tile still 64x128
//     (wm = wid*64, wn = 0): same 24 ds_read_b128, same verified swizzle
//     (0 conflicts), same MFMA cluster, same epilogue math.
//   - LDS 32 KB/block, ~224 regs/wave -> 4 independent blocks/CU: one
//     block's MFMA burst overlaps another's staging drain.
//   - grid (32, 64) = 2048 blocks; B re-fetch is LLC-resident (48 MB total).
//   Quantize kernel: original verified version, untouched.

typedef int int32x4 __attribute__((ext_vector_type(4)));

#define MDIM 8192
#define NDIM 4096
#define KDIM 4096

__device__ __forceinline__ void async_copy16(const void* g, void* l) {
  __builtin_amdgcn_global_load_lds(
      (const __attribute__((address_space(1))) void*)g,
      (__attribute__((address_space(3))) void*)l, 16, 0, 0);
}

__device__ __forceinline__ unsigned pack4(float a, float b, float c, float d) {
  return ((unsigned)((int)a & 0xff)) | ((unsigned)((int)b & 0xff) << 8) |
         ((unsigned)((int)c & 0xff) << 16) | ((unsigned)((int)d & 0xff) << 24);
}

// --- K1: fused quantizers. Blocks [0,4096): w rows; [4096,12288): x rows. ---
__global__ __launch_bounds__(256) void quantize_all(
    const float* __restrict__ w, const float* __restrict__ x,
    unsigned* __restrict__ qw, unsigned* __restrict__ qx,
    float* __restrict__ scale, float* __restrict__ sx) {
  const int t = threadIdx.x;
  __shared__ float wred[4];
  if (blockIdx.x < NDIM) {
    const int row = blockIdx.x;
    const float4* wr = (const float4*)(w + (size_t)row * KDIM);
    float4 v[4];
    float ss = 0.f;
#pragma unroll
    for (int i = 0; i < 4; ++i) {
      v[i] = wr[t + 256 * i];
      ss += v[i].x * v[i].x + v[i].y * v[i].y + v[i].z * v[i].z + v[i].w * v[i].w;
    }
#pragma unroll
    for (int m = 32; m >= 1; m >>= 1) ss += __shfl_xor(ss, m, 64);
    if ((t & 63) == 0) wred[t >> 6] = ss;
    __syncthreads();
    const float safe = fmaxf(sqrtf(wred[0] + wred[1] + wred[2] + wred[3]), 1e-8f);
    unsigned* qr = qw + (size_t)row * (KDIM / 4);
#pragma unroll
    for (int i = 0; i < 4; ++i) {
      float q0 = fminf(fmaxf(rintf(v[i].x / safe * 60.0f), -8.f), 7.f);
      float q1 = fminf(fmaxf(rintf(v[i].y / safe * 60.0f), -8.f), 7.f);
      float q2 = fminf(fmaxf(rintf(v[i].z / safe * 60.0f), -8.f), 7.f);
      float q3 = fminf(fmaxf(rintf(v[i].w / safe * 60.0f), -8.f), 7.f);
      qr[t + 256 * i] = pack4(q0, q1, q2, q3);
    }
    if (t == 0) scale[row] = safe / 60.0f;
  } else {
    const int row = blockIdx.x - NDIM;
    const float4* xr = (const float4*)(x + (size_t)row * KDIM);
    float4 v[4];
    float am = 0.f;
#pragma unroll
    for (int i = 0; i < 4; ++i) {
      v[i] = xr[t + 256 * i];
      am = fmaxf(am, fmaxf(fmaxf(fabsf(v[i].x), fabsf(v[i].y)),
                           fmaxf(fabsf(v[i].z), fabsf(v[i].w))));
    }
#pragma unroll
    for (int m = 32; m >= 1; m >>= 1) am = fmaxf(am, __shfl_xor(am, m, 64));
    if ((t & 63) == 0) wred[t >> 6] = am;
    __syncthreads();
    const float amax =
        fmaxf(fmaxf(fmaxf(wred[0], wred[1]), fmaxf(wred[2], wred[3])), 1e-20f);
    const float r = 127.0f / amax;
    unsigned* qr = qx + (size_t)row * (KDIM / 4);
#pragma unroll
    for (int i = 0; i < 4; ++i) {
      float q0 = fminf(fmaxf(rintf(v[i].x * r), -127.f), 127.f);
      float q1 = fminf(fmaxf(rintf(v[i].y * r), -127.f), 127.f);
      float q2 = fminf(fmaxf(rintf(v[i].z * r), -127.f), 127.f);
      float q3 = fminf(fmaxf(rintf(v[i].w * r), -127.f), 127.f);
      qr[t + 256 * i] = pack4(q0, q1, q2, q3);
    }
    if (t == 0) sx[row] = amax / 127.0f;
  }
}

// --- K2: C[m,n] = sx[m]*scale[n]*dot_i8(A[m,:],B[n,:]) + bias[n] ---
// Block tile 128(M) x 128(N), BK=128; 2 waves each 64x128 (acc 4x8).
// 4 independent blocks/CU for cross-block pipe overlap.
__global__ __launch_bounds__(128, 2) void gemm_i8(const char* __restrict__ A,
                                                  const char* __restrict__ B,
                                                  const float* __restrict__ sx,
                                                  const float* __restrict__ scale,
                                                  const float* __restrict__ bias,
                                                  float* __restrict__ C) {
  __shared__ __align__(16) char sA[128 * 128];  // 16 KB (x tile)
  __shared__ __align__(16) char sB[128 * 128];  // 16 KB (w tile)
  const int tid = threadIdx.x;
  const int m0 = blockIdx.y * 128;
  const int n0 = blockIdx.x * 128;

  // staging: thread t, issue i -> LDS byte i*2048 + t*16
  //   => row = i*16 + (t>>3), chunk = t&7; phys_chunk = chunk ^ (row&7)
  //   applied at the SOURCE ((t>>3)&7 == row&7 since 16|i*16).
  const int r0 = tid >> 3;                              // 0..15
  const int c16 = ((tid & 7) ^ ((tid >> 3) & 7)) * 16;  // swizzled source col
  const char* gA = A + (size_t)(m0 + r0) * KDIM + c16;
  const char* gB = B + (size_t)(n0 + r0) * KDIM + c16;
  char* lA = sA + tid * 16;
  char* lB = sB + tid * 16;

  const int lane = tid & 63;
  const int wid = tid >> 6;
  const int wm = wid * 64;   // wave M offset: 0 / 64
  const int fr = lane & 15;  // A: m, B: n
  const int q = lane >> 4;   // k-quad
  const int sw = fr & 7;
  const int ph0 = ((q) ^ sw) * 16;      // phys chunk offset, k-half 0
  const int ph1 = ((4 + q) ^ sw) * 16;  // phys chunk offset, k-half 1

  int32x4 acc[4][8] = {};

  for (int kt = 0; kt < KDIM / 128; ++kt) {  // 32 iterations
    __syncthreads();  // prior-iter LDS reads done before overwrite
#pragma unroll
    for (int i = 0; i < 8; ++i)
      async_copy16(gA + (size_t)(16 * i) * KDIM, lA + i * 2048);
#pragma unroll
    for (int i = 0; i < 8; ++i)
      async_copy16(gB + (size_t)(16 * i) * KDIM, lB + i * 2048);
    __syncthreads();  // vmcnt(0) drain + barrier
    gA += 128; gB += 128;

#pragma unroll
    for (int h = 0; h < 2; ++h) {
      const int ph = h ? ph1 : ph0;
      int32x4 af[4], bg[8];
#pragma unroll
      for (int i = 0; i < 4; ++i)
        af[i] = *(const int32x4*)&sA[(wm + i * 16 + fr) * 128 + ph];
#pragma unroll
      for (int j = 0; j < 8; ++j)
        bg[j] = *(const int32x4*)&sB[(j * 16 + fr) * 128 + ph];
#pragma unroll
      for (int i = 0; i < 4; ++i)
#pragma unroll
        for (int j = 0; j < 8; ++j)
          acc[i][j] =
              __builtin_amdgcn_mfma_i32_16x16x64_i8(af[i], bg[j], acc[i][j], 0, 0, 0);
    }
  }

  // epilogue: C/D layout col = lane&15, row = quad*4 + reg (shape-determined)
  float scl[8], bs[8];
#pragma unroll
  for (int j = 0; j < 8; ++j) {
    const int n = n0 + j * 16 + fr;
    scl[j] = scale[n];
    bs[j] = bias[n];
  }
  const int mrow = q * 4;
#pragma unroll
  for (int i = 0; i < 4; ++i) {
#pragma unroll
    for (int r = 0; r < 4; ++r) {
      const size_t m = (size_t)(m0 + wm + i * 16 + mrow + r);
      const float sxm = sx[m];
      float* crow = C + m * NDIM + (n0 + fr);
#pragma unroll
      for (int j = 0; j < 8; ++j)
        crow[j * 16] = (float)acc[i][j][r] * (sxm * scl[j]) + bs[j];
    }
  }
}

extern "C" void kernel_launch(void* const* d_in, const int* in_sizes, int n_in,
                              void* d_out, int out_size, void* d_ws, size_t ws_size,
                              hipStream_t stream) {
  (void)in_sizes; (void)n_in; (void)out_size; (void)ws_size;
  const float* x = (const float*)d_in[0];     // [8192, 4096] fp32
  const float* w = (const float*)d_in[1];     // [4096, 4096] fp32
  const float* bias = (const float*)d_in[2];  // [4096] fp32
  float* out = (float*)d_out;                 // [8192, 4096] fp32

  char* ws = (char*)d_ws;
  char* qx = ws;                                           // 32 MB int8
  char* qw = ws + (size_t)33554432;                        // 16 MB int8
  float* sx = (float*)(ws + (size_t)50331648);             // 32 KB
  float* scale = (float*)(ws + (size_t)50331648 + 65536);  // 16 KB

  quantize_all<<<NDIM + MDIM, 256, 0, stream>>>(w, x, (unsigned*)qw,
                                                (unsigned*)qx, scale, sx);
  dim3 grid(NDIM / 128, MDIM / 128);  // (32, 64)
  gemm_i8<<<grid, 128, 0, stream>>>(qx, qw, sx, scale, bias, out);
}